// Round 3
// baseline (4916.507 us; speedup 1.0000x reference)
//
#include <hip/hip_runtime.h>
#include <cstdint>
#include <cstddef>

#define M_ROWS 32768   // B*T
#define K_CODES 8192
#define H_DIM 512

#define BM 64
#define BN 128
#define BH 32
#define PADZ 4
#define PADE 4
#define TAU 2.5e-4f    // ~4 ulps at magnitude 512: flag for ideal-g np-order rescore
#define MAXFLAG 32768

// ---------------------------------------------------------------------------
// numpy pairwise sum-of-squares of a 512-row, bit-exact replication.
// numpy: PW(512) = PW(256lo)+PW(256hi); PW(256) = B(128lo)+B(128hi);
// B(128): r[j]=a[j]; r[j]+=a[8t+j] (t=1..15); ((r0+r1)+(r2+r3))+((r4+r5)+(r6+r7)).
// => x2 = (B0+B1)+(B2+B3). 32 lanes: lane L -> block c=L>>3, accumulator j=L&7.
// fp32 add is commutative bitwise, so xor-shuffle pairing is exact.
// ---------------------------------------------------------------------------
__device__ __forceinline__ float np_sumsq_row32(const float* __restrict__ row,
                                                int lane32) {
    const int c = lane32 >> 3, j = lane32 & 7;
    const float* p = row + c * 128 + j;
    float s = __fmul_rn(p[0], p[0]);
    #pragma unroll
    for (int t = 1; t < 16; ++t) {
        const float v = p[8 * t];
        s = __fadd_rn(s, __fmul_rn(v, v));
    }
    s = __fadd_rn(s, __shfl_xor(s, 1));   // (r_j + r_{j^1})
    s = __fadd_rn(s, __shfl_xor(s, 2));   // ((..)+(..))
    s = __fadd_rn(s, __shfl_xor(s, 4));   // full 128-block value Bc
    s = __fadd_rn(s, __shfl_xor(s, 8));   // (B0+B1), (B2+B3)
    s = __fadd_rn(s, __shfl_xor(s, 16));  // (B0+B1)+(B2+B3)
    return s;
}

// rows-of-squares kernel: 8 rows per 256-thread block (32 lanes per row)
__global__ __launch_bounds__(256) void rowsq_kernel(const float* __restrict__ src,
                                                    float* __restrict__ dst,
                                                    int nrows,
                                                    float* __restrict__ loss_slots,
                                                    int* __restrict__ flag_count,
                                                    int do_init) {
    const int r = blockIdx.x * 8 + (threadIdx.x >> 5);
    if (r < nrows) {
        const float s = np_sumsq_row32(src + (size_t)r * H_DIM, threadIdx.x & 31);
        if ((threadIdx.x & 31) == 0) dst[r] = s;
    }
    if (do_init && blockIdx.x == 0) {
        if (threadIdx.x < 2) loss_slots[threadIdx.x] = 0.f;
        if (threadIdx.x == 0) *flag_count = 0;
    }
}

// ---------------------------------------------------------------------------
// Stage R x BH fp32 tile transposed into LDS
// ---------------------------------------------------------------------------
__device__ __forceinline__ void stage_transposed(const float* __restrict__ src,
                                                 int row0, int h0,
                                                 float* lds, int R, int ldp) {
    const int nf4 = R * (BH / 4);
    for (int f = threadIdx.x; f < nf4; f += 256) {
        const int r  = f / (BH / 4);
        const int c4 = (f % (BH / 4)) * 4;
        const float4 v = *reinterpret_cast<const float4*>(
            src + (size_t)(row0 + r) * H_DIM + h0 + c4);
        lds[(c4 + 0) * ldp + r] = v.x;
        lds[(c4 + 1) * ldp + r] = v.y;
        lds[(c4 + 2) * ldp + r] = v.z;
        lds[(c4 + 3) * ldp + r] = v.w;
    }
}

// ---------------------------------------------------------------------------
// Fused distance-GEMM + per-row top-2 argmin with NP-ORDER rounding:
// d = fl( fl(x2 - 2*g) + e2 )   (fmaf(-2,g,x2) == fl(x2-2g) since 2g exact).
// First-occurrence tie-break. Rows with quantized top-2 gap < TAU get queued.
// ---------------------------------------------------------------------------
__global__ __launch_bounds__(256) void dist_argmin_kernel(
    const float* __restrict__ z, const float* __restrict__ emb,
    const float* __restrict__ x2, const float* __restrict__ e2,
    int* __restrict__ idx_i, float* __restrict__ idx_f,
    int* __restrict__ flag_count, int* __restrict__ flag_rows)
{
    __shared__ float zs[BH * (BM + PADZ)];
    __shared__ float es[BH * (BN + PADE)];
    __shared__ float bd[BM][17];
    __shared__ float bd2[BM][17];
    __shared__ int   bi[BM][17];

    const int row0 = blockIdx.x * BM;
    const int tx = threadIdx.x & 15;
    const int ty = threadIdx.x >> 4;

    float x2r[4];
    #pragma unroll
    for (int i = 0; i < 4; ++i) x2r[i] = x2[row0 + ty * 4 + i];

    float best[4], best2[4];
    int   bidx[4];
    #pragma unroll
    for (int i = 0; i < 4; ++i) { best[i] = 3.4e38f; best2[i] = 3.4e38f; bidx[i] = 0; }

    for (int nt = 0; nt < K_CODES / BN; ++nt) {
        float acc[4][8];
        #pragma unroll
        for (int i = 0; i < 4; ++i)
            #pragma unroll
            for (int j = 0; j < 8; ++j) acc[i][j] = 0.f;

        for (int hc = 0; hc < H_DIM / BH; ++hc) {
            __syncthreads();
            stage_transposed(z,   row0,    hc * BH, zs, BM, BM + PADZ);
            stage_transposed(emb, nt * BN, hc * BH, es, BN, BN + PADE);
            __syncthreads();
            #pragma unroll
            for (int h = 0; h < BH; ++h) {
                const float4 zr = *reinterpret_cast<const float4*>(&zs[h * (BM + PADZ) + ty * 4]);
                const float4 e0 = *reinterpret_cast<const float4*>(&es[h * (BN + PADE) + tx * 4]);
                const float4 e1 = *reinterpret_cast<const float4*>(&es[h * (BN + PADE) + 64 + tx * 4]);
                const float zrv[4] = {zr.x, zr.y, zr.z, zr.w};
                const float ev[8]  = {e0.x, e0.y, e0.z, e0.w, e1.x, e1.y, e1.z, e1.w};
                #pragma unroll
                for (int i = 0; i < 4; ++i)
                    #pragma unroll
                    for (int j = 0; j < 8; ++j)
                        acc[i][j] = fmaf(zrv[i], ev[j], acc[i][j]);
            }
        }

        #pragma unroll
        for (int j = 0; j < 8; ++j) {
            const int code = nt * BN + (j < 4 ? tx * 4 + j : 64 + tx * 4 + (j - 4));
            const float e2v = e2[code];
            #pragma unroll
            for (int i = 0; i < 4; ++i) {
                // np order: fl(fl(x2 - 2g) + e2)
                const float d = __fadd_rn(__fmaf_rn(-2.f, acc[i][j], x2r[i]), e2v);
                if (d < best[i])       { best2[i] = best[i]; best[i] = d; bidx[i] = code; }
                else if (d < best2[i]) { best2[i] = d; }   // d==best lands here -> gap 0
            }
        }
    }

    __syncthreads();
    #pragma unroll
    for (int i = 0; i < 4; ++i) {
        bd [ty * 4 + i][tx] = best[i];
        bd2[ty * 4 + i][tx] = best2[i];
        bi [ty * 4 + i][tx] = bidx[i];
    }
    __syncthreads();
    if (threadIdx.x < BM) {
        const int r = threadIdx.x;
        float g1 = bd[r][0]; int gi = bi[r][0]; float g2 = bd2[r][0];
        #pragma unroll
        for (int t = 1; t < 16; ++t) {
            const float v = bd[r][t]; const int x = bi[r][t];
            if (v < g1)       { g2 = g1; g1 = v; gi = x; }
            else if (v == g1) { g2 = g1; if (x < gi) gi = x; }
            else              { g2 = fminf(g2, v); }
            g2 = fminf(g2, bd2[r][t]);
        }
        idx_i[row0 + r] = gi;
        idx_f[row0 + r] = (float)gi;
        if (g2 - g1 < TAU) {
            const int p = atomicAdd(flag_count, 1);
            if (p < MAXFLAG) flag_rows[p] = row0 + r;
        }
    }
}

// ---------------------------------------------------------------------------
// Rescore flagged rows with IDEAL g (fp64 dot, rounded to fp32) under the
// exact np rounding order. Full 8192-code scan, first-occurrence tie-break.
// ---------------------------------------------------------------------------
__global__ __launch_bounds__(256) void fixup_kernel(
    const float* __restrict__ z, const float* __restrict__ emb,
    const float* __restrict__ x2, const float* __restrict__ e2,
    const int* __restrict__ flag_count, const int* __restrict__ flag_rows,
    int* __restrict__ idx_i, float* __restrict__ idx_f)
{
    __shared__ float zrow[H_DIM];
    __shared__ float sd[256];
    __shared__ int   si[256];
    int n = *flag_count; if (n > MAXFLAG) n = MAXFLAG;
    for (int j = blockIdx.x; j < n; j += gridDim.x) {
        const int row = flag_rows[j];
        __syncthreads();
        for (int h = threadIdx.x; h < H_DIM; h += 256)
            zrow[h] = z[(size_t)row * H_DIM + h];
        __syncthreads();
        const float x2r = x2[row];
        float bdv = 3.4e38f; int biv = 0x7fffffff;
        for (int k = threadIdx.x; k < K_CODES; k += 256) {
            const float* ek = emb + (size_t)k * H_DIM;
            double g = 0.0;
            for (int h = 0; h < H_DIM; ++h)
                g = fma((double)zrow[h], (double)ek[h], g);
            const float gf = (float)g;
            const float d = __fadd_rn(__fmaf_rn(-2.f, gf, x2r), e2[k]);
            if (d < bdv) { bdv = d; biv = k; }   // ascending k -> first occurrence
        }
        sd[threadIdx.x] = bdv; si[threadIdx.x] = biv;
        __syncthreads();
        for (int s = 128; s; s >>= 1) {
            if (threadIdx.x < s) {
                const float od = sd[threadIdx.x + s]; const int oi = si[threadIdx.x + s];
                if (od < sd[threadIdx.x] ||
                    (od == sd[threadIdx.x] && oi < si[threadIdx.x])) {
                    sd[threadIdx.x] = od; si[threadIdx.x] = oi;
                }
            }
            __syncthreads();
        }
        if (threadIdx.x == 0) {
            idx_i[row] = si[0];
            idx_f[row] = (float)si[0];
        }
        __syncthreads();
    }
}

// ---------------------------------------------------------------------------
// z_st = z + (z_q - z) + both losses (= mean((z_q - z)^2) forward)
// ---------------------------------------------------------------------------
__global__ __launch_bounds__(256) void epilogue_kernel(
    const float* __restrict__ z, const float* __restrict__ emb,
    const int* __restrict__ idx_i,
    float* __restrict__ z_st, float* __restrict__ loss_slots)
{
    const size_t N = (size_t)M_ROWS * H_DIM;
    float local = 0.f;
    for (size_t e = (size_t)blockIdx.x * blockDim.x + threadIdx.x; e < N;
         e += (size_t)gridDim.x * blockDim.x) {
        const size_t r = e >> 9;
        const int    h = (int)(e & 511);
        const float zq = emb[(size_t)idx_i[r] * H_DIM + h];
        const float zv = z[e];
        const float t  = zq - zv;
        z_st[e] = zv + t;
        local = fmaf(t, t, local);
    }
    #pragma unroll
    for (int off = 32; off; off >>= 1) local += __shfl_down(local, off);
    __shared__ float part[4];
    const int lane = threadIdx.x & 63, wid = threadIdx.x >> 6;
    if (lane == 0) part[wid] = local;
    __syncthreads();
    if (threadIdx.x == 0) {
        const float s = (part[0] + part[1] + part[2] + part[3]) * (1.f / (float)N);
        atomicAdd(&loss_slots[0], s);
        atomicAdd(&loss_slots[1], s);
    }
}

// ---------------------------------------------------------------------------
extern "C" void kernel_launch(void* const* d_in, const int* in_sizes, int n_in,
                              void* d_out, int out_size, void* d_ws, size_t ws_size,
                              hipStream_t stream) {
    const float* z   = (const float*)d_in[0];
    const float* emb = (const float*)d_in[1];

    float* out   = (float*)d_out;
    float* z_st  = out;
    float* idx_f = out + (size_t)M_ROWS * H_DIM;
    float* loss  = out + (size_t)M_ROWS * H_DIM + M_ROWS;

    char*  ws     = (char*)d_ws;
    float* e2     = (float*)ws;          ws += K_CODES * sizeof(float);
    float* x2     = (float*)ws;          ws += M_ROWS  * sizeof(float);
    int*   idx_i  = (int*)ws;            ws += M_ROWS  * sizeof(int);
    int*   fcount = (int*)ws;            ws += 4 * sizeof(int);
    int*   frows  = (int*)ws;

    hipLaunchKernelGGL(rowsq_kernel, dim3(K_CODES / 8), dim3(256), 0, stream,
                       emb, e2, K_CODES, loss, fcount, 1);
    hipLaunchKernelGGL(rowsq_kernel, dim3(M_ROWS / 8), dim3(256), 0, stream,
                       z, x2, M_ROWS, loss, fcount, 0);
    hipLaunchKernelGGL(dist_argmin_kernel, dim3(M_ROWS / BM), dim3(256), 0, stream,
                       z, emb, x2, e2, idx_i, idx_f, fcount, frows);
    hipLaunchKernelGGL(fixup_kernel, dim3(64), dim3(256), 0, stream,
                       z, emb, x2, e2, fcount, frows, idx_i, idx_f);
    hipLaunchKernelGGL(epilogue_kernel, dim3(2048), dim3(256), 0, stream,
                       z, emb, idx_i, z_st, loss);
}

// Round 4
// 1576.100 us; speedup vs baseline: 3.1194x; 3.1194x over previous
//
#include <hip/hip_runtime.h>
#include <cstdint>
#include <cstddef>

#define M_ROWS 32768   // B*T
#define K_CODES 8192
#define H_DIM 512
#define TAU 2.5e-4f
#define MAXFLAG 32768

typedef float  f32x4 __attribute__((ext_vector_type(4)));
typedef short  s16x8 __attribute__((ext_vector_type(8)));

typedef __attribute__((address_space(3))) void as3_void;
typedef const __attribute__((address_space(1))) void as1_cvoid;
#define GLD16(gp, lp) __builtin_amdgcn_global_load_lds((as1_cvoid*)(gp), (as3_void*)(lp), 16, 0, 0)

// ---------------------------------------------------------------------------
// bf16 split helpers (RNE)
// ---------------------------------------------------------------------------
__device__ __forceinline__ unsigned short f2bf(float f) {
    uint32_t u = __float_as_uint(f);
    u = u + 0x7fffu + ((u >> 16) & 1u);
    return (unsigned short)(u >> 16);
}
__device__ __forceinline__ float bf2f(unsigned short h) {
    return __uint_as_float(((uint32_t)h) << 16);
}

// split fp32 -> (hi, lo) bf16; 4 elems/thread
__global__ __launch_bounds__(256) void split_kernel(const float* __restrict__ src,
                                                    unsigned short* __restrict__ hi,
                                                    unsigned short* __restrict__ lo,
                                                    int n4) {
    const int t = blockIdx.x * 256 + threadIdx.x;
    if (t >= n4) return;
    const float4 v = reinterpret_cast<const float4*>(src)[t];
    ushort4 h, l;
    {
        h.x = f2bf(v.x); l.x = f2bf(v.x - bf2f(h.x));
        h.y = f2bf(v.y); l.y = f2bf(v.y - bf2f(h.y));
        h.z = f2bf(v.z); l.z = f2bf(v.z - bf2f(h.z));
        h.w = f2bf(v.w); l.w = f2bf(v.w - bf2f(h.w));
    }
    reinterpret_cast<ushort4*>(hi)[t] = h;
    reinterpret_cast<ushort4*>(lo)[t] = l;
}

// ---------------------------------------------------------------------------
// numpy pairwise sum-of-squares (bit-exact), 32 lanes per row — unchanged (r3)
// ---------------------------------------------------------------------------
__device__ __forceinline__ float np_sumsq_row32(const float* __restrict__ row,
                                                int lane32) {
    const int c = lane32 >> 3, j = lane32 & 7;
    const float* p = row + c * 128 + j;
    float s = __fmul_rn(p[0], p[0]);
    #pragma unroll
    for (int t = 1; t < 16; ++t) {
        const float v = p[8 * t];
        s = __fadd_rn(s, __fmul_rn(v, v));
    }
    s = __fadd_rn(s, __shfl_xor(s, 1));
    s = __fadd_rn(s, __shfl_xor(s, 2));
    s = __fadd_rn(s, __shfl_xor(s, 4));
    s = __fadd_rn(s, __shfl_xor(s, 8));
    s = __fadd_rn(s, __shfl_xor(s, 16));
    return s;
}

__global__ __launch_bounds__(256) void rowsq_kernel(const float* __restrict__ src,
                                                    float* __restrict__ dst,
                                                    int nrows,
                                                    float* __restrict__ loss_slots,
                                                    int* __restrict__ flag_count,
                                                    int do_init) {
    const int r = blockIdx.x * 8 + (threadIdx.x >> 5);
    if (r < nrows) {
        const float s = np_sumsq_row32(src + (size_t)r * H_DIM, threadIdx.x & 31);
        if ((threadIdx.x & 31) == 0) dst[r] = s;
    }
    if (do_init && blockIdx.x == 0) {
        if (threadIdx.x < 2) loss_slots[threadIdx.x] = 0.f;
        if (threadIdx.x == 0) *flag_count = 0;
    }
}

// ---------------------------------------------------------------------------
// top-2 merge helper: (b1,ix,b2) <- merge with (ob1,oix,ob2); tie -> lower idx
// ---------------------------------------------------------------------------
__device__ __forceinline__ void top2_merge(float& b1, int& ix, float& b2,
                                           float ob1, int oix, float ob2) {
    if (ob1 < b1)      { b2 = fminf(b1, ob2); b1 = ob1; ix = oix; }
    else if (ob1 > b1) { b2 = fminf(b2, ob1); }
    else               { if (oix < ix) ix = oix; b2 = b1; }
}

// ---------------------------------------------------------------------------
// MFMA distance GEMM + per-row top-2 argmin (split-2 bf16, 3 products).
// Tile: 128 rows x 128 codes, BK=64, 4 waves (2m x 2n), grid (M/128, 2).
// LDS: Ah/Al/Bh/Bl [128][64] bf16, XOR-swizzled 16B chunks (k16 ^= row&7);
// staged via global_load_lds w/ pre-swizzled per-lane global source.
// d = fl(fl(x2 - 2g) + e2)  (np rounding order).
// ---------------------------------------------------------------------------
__global__ __launch_bounds__(256, 2) void mfma_dist_kernel(
    const unsigned short* __restrict__ zh, const unsigned short* __restrict__ zl,
    const unsigned short* __restrict__ eh, const unsigned short* __restrict__ el,
    const float* __restrict__ x2, const float* __restrict__ e2,
    float* __restrict__ pb1, float* __restrict__ pb2, int* __restrict__ pidx)
{
    __shared__ __align__(16) unsigned short lb[4][8192];   // 64 KiB
    __shared__ float rb1[2][128];
    __shared__ float rb2[2][128];
    __shared__ int   ri [2][128];

    const int tid = threadIdx.x;
    const int l   = tid & 63;
    const int w   = tid >> 6;
    const int wm  = w >> 1, wn = w & 1;
    const int row0 = blockIdx.x * 128;
    const int c0   = blockIdx.y * (K_CODES / 2);
    const int NT   = (K_CODES / 2) / 128;   // 32

    const unsigned short* sp = (w == 0) ? zh : (w == 1) ? zl : (w == 2) ? eh : el;
    const int srow = l >> 3;
    const int scol = ((l & 7) ^ srow) * 8;           // swizzled k-element offset

    const int abase = (wm * 64 + (l & 15)) * 128;    // bytes into A buffers
    const int bbase = (wn * 64 + (l & 15)) * 128;
    int axor[2];
    axor[0] = (((l >> 4))     ^ (l & 7)) * 16;
    axor[1] = ((4 + (l >> 4)) ^ (l & 7)) * 16;

    float x2r[16];
    #pragma unroll
    for (int i = 0; i < 4; ++i)
        #pragma unroll
        for (int r = 0; r < 4; ++r)
            x2r[i * 4 + r] = x2[row0 + wm * 64 + i * 16 + (l >> 4) * 4 + r];

    float tb1[16], tb2[16]; int tix[16];
    #pragma unroll
    for (int s = 0; s < 16; ++s) { tb1[s] = 3.4e38f; tb2[s] = 3.4e38f; tix[s] = 0; }

    char* lA  = (char*)&lb[0][0];
    char* lAl = (char*)&lb[1][0];
    char* lB  = (char*)&lb[2][0];
    char* lBl = (char*)&lb[3][0];

    for (int nt = 0; nt < NT; ++nt) {
        f32x4 acc[4][4];
        #pragma unroll
        for (int i = 0; i < 4; ++i)
            #pragma unroll
            for (int j = 0; j < 4; ++j)
                acc[i][j] = (f32x4){0.f, 0.f, 0.f, 0.f};

        const int rbase = (w < 2) ? row0 : (c0 + nt * 128);
        const unsigned short* srcbase = sp + (size_t)(rbase + srow) * H_DIM + scol;

        for (int hc = 0; hc < 8; ++hc) {
            __syncthreads();
            #pragma unroll
            for (int t = 0; t < 16; ++t)
                GLD16(srcbase + (size_t)t * 8 * H_DIM + hc * 64,
                      (char*)&lb[w][0] + t * 1024);
            asm volatile("s_waitcnt vmcnt(0)" ::: "memory");
            __syncthreads();

            #pragma unroll
            for (int kk = 0; kk < 2; ++kk) {
                s16x8 ah[4], av[4], bh[4], bv[4];
                #pragma unroll
                for (int i = 0; i < 4; ++i) {
                    ah[i] = *(const s16x8*)(lA  + abase + i * 2048 + axor[kk]);
                    av[i] = *(const s16x8*)(lAl + abase + i * 2048 + axor[kk]);
                    bh[i] = *(const s16x8*)(lB  + bbase + i * 2048 + axor[kk]);
                    bv[i] = *(const s16x8*)(lBl + bbase + i * 2048 + axor[kk]);
                }
                #pragma unroll
                for (int i = 0; i < 4; ++i)
                    #pragma unroll
                    for (int j = 0; j < 4; ++j) {
                        acc[i][j] = __builtin_amdgcn_mfma_f32_16x16x32_bf16(av[i], bh[j], acc[i][j], 0, 0, 0);
                        acc[i][j] = __builtin_amdgcn_mfma_f32_16x16x32_bf16(ah[i], bv[j], acc[i][j], 0, 0, 0);
                        acc[i][j] = __builtin_amdgcn_mfma_f32_16x16x32_bf16(ah[i], bh[j], acc[i][j], 0, 0, 0);
                    }
            }
        }

        // fold e2, np-order d, update per-lane top-2 (codes ascend with j, nt)
        #pragma unroll
        for (int j = 0; j < 4; ++j) {
            const int cj = c0 + nt * 128 + wn * 64 + j * 16 + (l & 15);
            const float e2v = e2[cj];
            #pragma unroll
            for (int i = 0; i < 4; ++i)
                #pragma unroll
                for (int r = 0; r < 4; ++r) {
                    const float d = __fadd_rn(__fmaf_rn(-2.f, acc[i][j][r], x2r[i * 4 + r]), e2v);
                    const int s = i * 4 + r;
                    if (d < tb1[s])      { tb2[s] = tb1[s]; tb1[s] = d; tix[s] = cj; }
                    else if (d < tb2[s]) { tb2[s] = d; }
                }
        }
    }

    // 16-lane (same l>>4 group) top-2 reduce per state
    #pragma unroll
    for (int s = 0; s < 16; ++s) {
        float b1 = tb1[s], b2 = tb2[s]; int ix = tix[s];
        #pragma unroll
        for (int m = 1; m <= 8; m <<= 1) {
            const float ob1 = __shfl_xor(b1, m);
            const float ob2 = __shfl_xor(b2, m);
            const int   oix = __shfl_xor(ix, m);
            top2_merge(b1, ix, b2, ob1, oix, ob2);
        }
        tb1[s] = b1; tb2[s] = b2; tix[s] = ix;
    }
    if ((l & 15) == 0) {
        const int q = l >> 4;
        #pragma unroll
        for (int i = 0; i < 4; ++i)
            #pragma unroll
            for (int r = 0; r < 4; ++r) {
                const int rl = wm * 64 + i * 16 + q * 4 + r;
                rb1[wn][rl] = tb1[i * 4 + r];
                rb2[wn][rl] = tb2[i * 4 + r];
                ri [wn][rl] = tix[i * 4 + r];
            }
    }
    __syncthreads();
    if (tid < 128) {
        float b1 = rb1[0][tid], b2 = rb2[0][tid]; int ix = ri[0][tid];
        top2_merge(b1, ix, b2, rb1[1][tid], ri[1][tid], rb2[1][tid]);
        const size_t o = (size_t)blockIdx.y * M_ROWS + row0 + tid;
        pb1[o] = b1; pb2[o] = b2; pidx[o] = ix;
    }
}

// merge the 2 code-split partials per row; emit idx + ambiguity flags
__global__ __launch_bounds__(256) void combine_kernel(
    const float* __restrict__ pb1, const float* __restrict__ pb2,
    const int* __restrict__ pidx,
    int* __restrict__ idx_i, float* __restrict__ idx_f,
    int* __restrict__ flag_count, int* __restrict__ flag_rows)
{
    const int r = blockIdx.x * 256 + threadIdx.x;
    if (r >= M_ROWS) return;
    float b1 = pb1[r], b2 = pb2[r]; int ix = pidx[r];
    top2_merge(b1, ix, b2, pb1[M_ROWS + r], pidx[M_ROWS + r], pb2[M_ROWS + r]);
    idx_i[r] = ix;
    idx_f[r] = (float)ix;
    if (b2 - b1 < TAU) {
        const int p = atomicAdd(flag_count, 1);
        if (p < MAXFLAG) flag_rows[p] = r;
    }
}

// ---------------------------------------------------------------------------
// FALLBACK (round-3 fp32 path) — used only if ws_size is too small
// ---------------------------------------------------------------------------
#define BM 64
#define BN 128
#define BH 32
#define PADZ 4
#define PADE 4

__device__ __forceinline__ void stage_transposed(const float* __restrict__ src,
                                                 int row0, int h0,
                                                 float* lds, int R, int ldp) {
    const int nf4 = R * (BH / 4);
    for (int f = threadIdx.x; f < nf4; f += 256) {
        const int r  = f / (BH / 4);
        const int c4 = (f % (BH / 4)) * 4;
        const float4 v = *reinterpret_cast<const float4*>(
            src + (size_t)(row0 + r) * H_DIM + h0 + c4);
        lds[(c4 + 0) * ldp + r] = v.x;
        lds[(c4 + 1) * ldp + r] = v.y;
        lds[(c4 + 2) * ldp + r] = v.z;
        lds[(c4 + 3) * ldp + r] = v.w;
    }
}

__global__ __launch_bounds__(256) void dist_argmin_kernel(
    const float* __restrict__ z, const float* __restrict__ emb,
    const float* __restrict__ x2, const float* __restrict__ e2,
    int* __restrict__ idx_i, float* __restrict__ idx_f,
    int* __restrict__ flag_count, int* __restrict__ flag_rows)
{
    __shared__ float zs[BH * (BM + PADZ)];
    __shared__ float es[BH * (BN + PADE)];
    __shared__ float bd[BM][17];
    __shared__ float bd2[BM][17];
    __shared__ int   bi[BM][17];

    const int row0 = blockIdx.x * BM;
    const int tx = threadIdx.x & 15;
    const int ty = threadIdx.x >> 4;

    float x2r[4];
    #pragma unroll
    for (int i = 0; i < 4; ++i) x2r[i] = x2[row0 + ty * 4 + i];

    float best[4], best2[4];
    int   bidx[4];
    #pragma unroll
    for (int i = 0; i < 4; ++i) { best[i] = 3.4e38f; best2[i] = 3.4e38f; bidx[i] = 0; }

    for (int nt = 0; nt < K_CODES / BN; ++nt) {
        float acc[4][8];
        #pragma unroll
        for (int i = 0; i < 4; ++i)
            #pragma unroll
            for (int j = 0; j < 8; ++j) acc[i][j] = 0.f;

        for (int hc = 0; hc < H_DIM / BH; ++hc) {
            __syncthreads();
            stage_transposed(z,   row0,    hc * BH, zs, BM, BM + PADZ);
            stage_transposed(emb, nt * BN, hc * BH, es, BN, BN + PADE);
            __syncthreads();
            #pragma unroll
            for (int h = 0; h < BH; ++h) {
                const float4 zr = *reinterpret_cast<const float4*>(&zs[h * (BM + PADZ) + ty * 4]);
                const float4 e0 = *reinterpret_cast<const float4*>(&es[h * (BN + PADE) + tx * 4]);
                const float4 e1 = *reinterpret_cast<const float4*>(&es[h * (BN + PADE) + 64 + tx * 4]);
                const float zrv[4] = {zr.x, zr.y, zr.z, zr.w};
                const float ev[8]  = {e0.x, e0.y, e0.z, e0.w, e1.x, e1.y, e1.z, e1.w};
                #pragma unroll
                for (int i = 0; i < 4; ++i)
                    #pragma unroll
                    for (int j = 0; j < 8; ++j)
                        acc[i][j] = fmaf(zrv[i], ev[j], acc[i][j]);
            }
        }
        #pragma unroll
        for (int j = 0; j < 8; ++j) {
            const int code = nt * BN + (j < 4 ? tx * 4 + j : 64 + tx * 4 + (j - 4));
            const float e2v = e2[code];
            #pragma unroll
            for (int i = 0; i < 4; ++i) {
                const float d = __fadd_rn(__fmaf_rn(-2.f, acc[i][j], x2r[i]), e2v);
                if (d < best[i])       { best2[i] = best[i]; best[i] = d; bidx[i] = code; }
                else if (d < best2[i]) { best2[i] = d; }
            }
        }
    }

    __syncthreads();
    #pragma unroll
    for (int i = 0; i < 4; ++i) {
        bd [ty * 4 + i][tx] = best[i];
        bd2[ty * 4 + i][tx] = best2[i];
        bi [ty * 4 + i][tx] = bidx[i];
    }
    __syncthreads();
    if (threadIdx.x < BM) {
        const int r = threadIdx.x;
        float g1 = bd[r][0]; int gi = bi[r][0]; float g2 = bd2[r][0];
        #pragma unroll
        for (int t = 1; t < 16; ++t) {
            const float v = bd[r][t]; const int x = bi[r][t];
            if (v < g1)       { g2 = g1; g1 = v; gi = x; }
            else if (v == g1) { g2 = g1; if (x < gi) gi = x; }
            else              { g2 = fminf(g2, v); }
            g2 = fminf(g2, bd2[r][t]);
        }
        idx_i[row0 + r] = gi;
        idx_f[row0 + r] = (float)gi;
        if (g2 - g1 < TAU) {
            const int p = atomicAdd(flag_count, 1);
            if (p < MAXFLAG) flag_rows[p] = row0 + r;
        }
    }
}

// ---------------------------------------------------------------------------
// fixup: ideal-g (fp64 dot -> fp32) rescore of flagged rows, np rounding order
// ---------------------------------------------------------------------------
__global__ __launch_bounds__(256) void fixup_kernel(
    const float* __restrict__ z, const float* __restrict__ emb,
    const float* __restrict__ x2, const float* __restrict__ e2,
    const int* __restrict__ flag_count, const int* __restrict__ flag_rows,
    int* __restrict__ idx_i, float* __restrict__ idx_f)
{
    __shared__ float zrow[H_DIM];
    __shared__ float sd[256];
    __shared__ int   si[256];
    int n = *flag_count; if (n > MAXFLAG) n = MAXFLAG;
    for (int j = blockIdx.x; j < n; j += gridDim.x) {
        const int row = flag_rows[j];
        __syncthreads();
        for (int h = threadIdx.x; h < H_DIM; h += 256)
            zrow[h] = z[(size_t)row * H_DIM + h];
        __syncthreads();
        const float x2r = x2[row];
        float bdv = 3.4e38f; int biv = 0x7fffffff;
        for (int k = threadIdx.x; k < K_CODES; k += 256) {
            const float* ek = emb + (size_t)k * H_DIM;
            double g = 0.0;
            for (int h = 0; h < H_DIM; ++h)
                g = fma((double)zrow[h], (double)ek[h], g);
            const float gf = (float)g;
            const float d = __fadd_rn(__fmaf_rn(-2.f, gf, x2r), e2[k]);
            if (d < bdv) { bdv = d; biv = k; }
        }
        sd[threadIdx.x] = bdv; si[threadIdx.x] = biv;
        __syncthreads();
        for (int s = 128; s; s >>= 1) {
            if (threadIdx.x < s) {
                const float od = sd[threadIdx.x + s]; const int oi = si[threadIdx.x + s];
                if (od < sd[threadIdx.x] ||
                    (od == sd[threadIdx.x] && oi < si[threadIdx.x])) {
                    sd[threadIdx.x] = od; si[threadIdx.x] = oi;
                }
            }
            __syncthreads();
        }
        if (threadIdx.x == 0) { idx_i[row] = si[0]; idx_f[row] = (float)si[0]; }
        __syncthreads();
    }
}

// ---------------------------------------------------------------------------
// z_st = z + (z_q - z) + both losses
// ---------------------------------------------------------------------------
__global__ __launch_bounds__(256) void epilogue_kernel(
    const float* __restrict__ z, const float* __restrict__ emb,
    const int* __restrict__ idx_i,
    float* __restrict__ z_st, float* __restrict__ loss_slots)
{
    const size_t N = (size_t)M_ROWS * H_DIM;
    float local = 0.f;
    for (size_t e = (size_t)blockIdx.x * blockDim.x + threadIdx.x; e < N;
         e += (size_t)gridDim.x * blockDim.x) {
        const size_t r = e >> 9;
        const int    h = (int)(e & 511);
        const float zq = emb[(size_t)idx_i[r] * H_DIM + h];
        const float zv = z[e];
        const float t  = zq - zv;
        z_st[e] = zv + t;
        local = fmaf(t, t, local);
    }
    #pragma unroll
    for (int off = 32; off; off >>= 1) local += __shfl_down(local, off);
    __shared__ float part[4];
    const int lane = threadIdx.x & 63, wid = threadIdx.x >> 6;
    if (lane == 0) part[wid] = local;
    __syncthreads();
    if (threadIdx.x == 0) {
        const float s = (part[0] + part[1] + part[2] + part[3]) * (1.f / (float)N);
        atomicAdd(&loss_slots[0], s);
        atomicAdd(&loss_slots[1], s);
    }
}

// ---------------------------------------------------------------------------
extern "C" void kernel_launch(void* const* d_in, const int* in_sizes, int n_in,
                              void* d_out, int out_size, void* d_ws, size_t ws_size,
                              hipStream_t stream) {
    const float* z   = (const float*)d_in[0];
    const float* emb = (const float*)d_in[1];

    float* out   = (float*)d_out;
    float* z_st  = out;
    float* idx_f = out + (size_t)M_ROWS * H_DIM;
    float* loss  = out + (size_t)M_ROWS * H_DIM + M_ROWS;

    char* ws = (char*)d_ws;
    float* e2     = (float*)(ws + 0);            // 32 KiB
    float* x2     = (float*)(ws + 32768);        // 128 KiB
    int*   idx_i  = (int*)  (ws + 163840);       // 128 KiB
    int*   fcount = (int*)  (ws + 294912);       // 64 B
    int*   frows  = (int*)  (ws + 294976);       // 128 KiB
    float* pb1    = (float*)(ws + 426048);       // 256 KiB
    float* pb2    = (float*)(ws + 688192);       // 256 KiB
    int*   pidx   = (int*)  (ws + 950336);       // 256 KiB
    unsigned short* zh = (unsigned short*)(ws + 1212480);
    unsigned short* zl = (unsigned short*)(ws + 1212480 + 33554432ull);
    unsigned short* eh = (unsigned short*)(ws + 1212480 + 67108864ull);
    unsigned short* el = (unsigned short*)(ws + 1212480 + 75497472ull);
    const size_t REQ = 1212480ull + 75497472ull + 8388608ull;   // ~85.1 MB

    hipLaunchKernelGGL(rowsq_kernel, dim3(K_CODES / 8), dim3(256), 0, stream,
                       emb, e2, K_CODES, loss, fcount, 1);
    hipLaunchKernelGGL(rowsq_kernel, dim3(M_ROWS / 8), dim3(256), 0, stream,
                       z, x2, M_ROWS, loss, fcount, 0);

    if (ws_size >= REQ) {
        hipLaunchKernelGGL(split_kernel, dim3((M_ROWS * H_DIM / 4) / 256), dim3(256), 0, stream,
                           z, zh, zl, M_ROWS * H_DIM / 4);
        hipLaunchKernelGGL(split_kernel, dim3((K_CODES * H_DIM / 4) / 256), dim3(256), 0, stream,
                           emb, eh, el, K_CODES * H_DIM / 4);
        hipLaunchKernelGGL(mfma_dist_kernel, dim3(M_ROWS / 128, 2), dim3(256), 0, stream,
                           zh, zl, eh, el, x2, e2, pb1, pb2, pidx);
        hipLaunchKernelGGL(combine_kernel, dim3(M_ROWS / 256), dim3(256), 0, stream,
                           pb1, pb2, pidx, idx_i, idx_f, fcount, frows);
    } else {
        hipLaunchKernelGGL(dist_argmin_kernel, dim3(M_ROWS / BM), dim3(256), 0, stream,
                           z, emb, x2, e2, idx_i, idx_f, fcount, frows);
    }

    hipLaunchKernelGGL(fixup_kernel, dim3(64), dim3(256), 0, stream,
                       z, emb, x2, e2, fcount, frows, idx_i, idx_f);
    hipLaunchKernelGGL(epilogue_kernel, dim3(2048), dim3(256), 0, stream,
                       z, emb, idx_i, z_st, loss);
}